// Round 13
// baseline (219.548 us; speedup 1.0000x reference)
//
#include <hip/hip_runtime.h>
#include <hip/hip_fp16.h>

#define N_NODES 50000
#define N_EDGES 800000
#define IN_DIM 128
#define HID 64
#define NUM_GRAPHS 64
#define POOL_BLOCKS 512
#define NB 196        // buckets: dst >> 8 (256 node-ids per bucket)
#define NBLK 256      // blocks in hist/bin passes (edge->block map must match)

__device__ inline float4 load_h4(const __half* p) {
    const __half2* q = (const __half2*)p;
    float2 a = __half22float2(q[0]);
    float2 b = __half22float2(q[1]);
    return make_float4(a.x, a.y, b.x, b.y);
}
__device__ inline void store_h4(__half* p, float4 v) {
    __half2* q = (__half2*)p;
    q[0] = __floats2half2_rn(v.x, v.y);
    q[1] = __floats2half2_rn(v.z, v.w);
}

// Pass 1: per-block LDS histogram over NB buckets. hist_g[b*NBLK + blk] = count.
__global__ __launch_bounds__(256) void hist_kernel(const int* __restrict__ dst, int* __restrict__ hist_g) {
    __shared__ int h[NB];
    int tid = threadIdx.x;
    for (int i = tid; i < NB; i += 256) h[i] = 0;
    __syncthreads();
    const int NI = N_EDGES / 4;
    for (int i = blockIdx.x * 256 + tid; i < NI; i += NBLK * 256) {
        int4 d = ((const int4*)dst)[i];
        atomicAdd(&h[d.x >> 8], 1);
        atomicAdd(&h[d.y >> 8], 1);
        atomicAdd(&h[d.z >> 8], 1);
        atomicAdd(&h[d.w >> 8], 1);
    }
    __syncthreads();
    for (int i = tid; i < NB; i += 256) hist_g[i * NBLK + blockIdx.x] = h[i];
}

// Pass 2: single-block exclusive scan of hist_g (bucket-major, L = NB*NBLK ints).
__global__ __launch_bounds__(1024) void scan2_kernel(const int* __restrict__ in, int* __restrict__ pos,
                                                     int* __restrict__ offs) {
    __shared__ int wsum[16];
    __shared__ int tot_s;
    int tid = threadIdx.x;
    int lane = tid & 63, wid = tid >> 6;
    int carry = 0;
    const int L = NB * NBLK;                   // 50176, divisible by 4
    for (int base = 0; base < L; base += 4096) {
        int idx = base + tid * 4;
        int v0 = 0, v1 = 0, v2 = 0, v3 = 0;
        if (idx < L) { int4 v = *(const int4*)&in[idx]; v0 = v.x; v1 = v.y; v2 = v.z; v3 = v.w; }
        int s0 = v0, s1 = s0 + v1, s2 = s1 + v2, s3 = s2 + v3;
        int inc = s3;
        #pragma unroll
        for (int d = 1; d < 64; d <<= 1) { int t = __shfl_up(inc, d, 64); if (lane >= d) inc += t; }
        if (lane == 63) wsum[wid] = inc;
        __syncthreads();
        if (tid < 16) {
            int wv = wsum[tid], winc = wv;
            #pragma unroll
            for (int d = 1; d < 16; d <<= 1) { int t = __shfl_up(winc, d, 16); if (tid >= d) winc += t; }
            wsum[tid] = winc - wv;
            if (tid == 15) tot_s = winc;
        }
        __syncthreads();
        int excl = carry + wsum[wid] + inc - s3;
        if (idx < L) { int4 o; o.x = excl; o.y = excl + s0; o.z = excl + s1; o.w = excl + s2; *(int4*)&pos[idx] = o; }
        carry += tot_s;
    }
    if (tid == 0) offs[N_NODES] = N_EDGES;
}

// Pass 3: bin edges bucket-major, packed 4B: src(16b) | (dst&255)<<16.
__global__ __launch_bounds__(256) void bin_kernel(const int* __restrict__ src, const int* __restrict__ dst,
                                                  const int* __restrict__ pos, int* __restrict__ binned) {
    __shared__ int cur[NB];
    int tid = threadIdx.x;
    for (int i = tid; i < NB; i += 256) cur[i] = pos[i * NBLK + blockIdx.x];
    __syncthreads();
    const int NI = N_EDGES / 4;
    for (int i = blockIdx.x * 256 + tid; i < NI; i += NBLK * 256) {
        int4 s = ((const int4*)src)[i];
        int4 d = ((const int4*)dst)[i];
        int p0 = atomicAdd(&cur[d.x >> 8], 1); binned[p0] = (s.x & 0xFFFF) | ((d.x & 255) << 16);
        int p1 = atomicAdd(&cur[d.y >> 8], 1); binned[p1] = (s.y & 0xFFFF) | ((d.y & 255) << 16);
        int p2 = atomicAdd(&cur[d.z >> 8], 1); binned[p2] = (s.z & 0xFFFF) | ((d.z & 255) << 16);
        int p3 = atomicAdd(&cur[d.w >> 8], 1); binned[p3] = (s.w & 0xFFFF) | ((d.w & 255) << 16);
    }
}

// Pass 4: one block per bucket — LDS counting sort by local id; writes offs, dinv, csr_src.
__global__ __launch_bounds__(256) void build_kernel(const int* __restrict__ binned, const int* __restrict__ pos,
                                                    int* __restrict__ offs, float* __restrict__ dinv,
                                                    int* __restrict__ csr_src) {
    __shared__ int cnt[256];
    __shared__ int excl[256];
    __shared__ int rnk[256];
    __shared__ int wtot[4];
    int b = blockIdx.x, tid = threadIdx.x;
    int base = pos[b * NBLK];
    int end  = (b == NB - 1) ? N_EDGES : pos[(b + 1) * NBLK];
    cnt[tid] = 0; rnk[tid] = 0;
    __syncthreads();
    for (int j = base + tid; j < end; j += 256) atomicAdd(&cnt[(binned[j] >> 16) & 255], 1);
    __syncthreads();
    int v = cnt[tid];
    int lane = tid & 63, wid = tid >> 6;
    int inc = v;
    #pragma unroll
    for (int d = 1; d < 64; d <<= 1) { int t = __shfl_up(inc, d, 64); if (lane >= d) inc += t; }
    if (lane == 63) wtot[wid] = inc;
    __syncthreads();
    if (tid == 0) {
        int a = 0;
        for (int w = 0; w < 4; w++) { int t = wtot[w]; wtot[w] = a; a += t; }
    }
    __syncthreads();
    excl[tid] = wtot[wid] + inc - v;
    int node = b * 256 + tid;
    if (node < N_NODES) {
        offs[node] = base + excl[tid];
        dinv[node] = rsqrtf((float)v + 1.0f);
    }
    __syncthreads();
    for (int j = base + tid; j < end; j += 256) {
        int e = binned[j];
        int l = (e >> 16) & 255;
        int r = atomicAdd(&rnk[l], 1);
        csr_src[base + excl[l] + r] = e & 0xFFFF;
    }
}

// C = (A[nRows,K] @ W[K,64]) * dinv[n] -> fp16.
// Block: 64 nodes x 64 cols; thread = 4 nodes x 4 contiguous cols. [round-12 proven shape]
template <int K, typename TIN>
__global__ __launch_bounds__(256) void gemm_kernel(const TIN* __restrict__ A, const float* __restrict__ W,
                                                   const float* __restrict__ dinv,
                                                   __half* __restrict__ out, int nRows) {
    constexpr int KB = 64;
    constexpr int KBP = KB + 4;               // 68
    __shared__ float xs[64 * KBP];
    __shared__ float ws[KB * 68];
    int tid = threadIdx.x;
    int node0 = blockIdx.x * 64;
    int c0 = (tid & 15) * 4, n0 = (tid >> 4) * 4;
    float acc[4][4] = {};
    for (int kb = 0; kb < K; kb += KB) {
        for (int i = tid; i < KB * 16; i += 256) {
            int k = i >> 4, c4 = (i & 15) * 4;
            *(float4*)&ws[k * 68 + c4] = *(const float4*)&W[(size_t)(kb + k) * 64 + c4];
        }
        for (int i = tid; i < 64 * (KB / 4); i += 256) {
            int n = i / (KB / 4), k4 = (i % (KB / 4)) * 4;
            int gn = node0 + n;
            float4 v;
            if (gn < nRows) {
                if constexpr (sizeof(TIN) == 4) v = *(const float4*)&A[(size_t)gn * K + kb + k4];
                else                            v = load_h4((const __half*)&A[(size_t)gn * K + kb + k4]);
            } else v = make_float4(0.f, 0.f, 0.f, 0.f);
            *(float4*)&xs[n * KBP + k4] = v;
        }
        __syncthreads();
        for (int k = 0; k < KB; k += 4) {
            float4 x0 = *(const float4*)&xs[(n0 + 0) * KBP + k];
            float4 x1 = *(const float4*)&xs[(n0 + 1) * KBP + k];
            float4 x2 = *(const float4*)&xs[(n0 + 2) * KBP + k];
            float4 x3 = *(const float4*)&xs[(n0 + 3) * KBP + k];
            #define KSTEP(KK, F) { \
                float4 wr = *(const float4*)&ws[(k + KK) * 68 + c0]; \
                acc[0][0] += x0.F * wr.x; acc[0][1] += x0.F * wr.y; acc[0][2] += x0.F * wr.z; acc[0][3] += x0.F * wr.w; \
                acc[1][0] += x1.F * wr.x; acc[1][1] += x1.F * wr.y; acc[1][2] += x1.F * wr.z; acc[1][3] += x1.F * wr.w; \
                acc[2][0] += x2.F * wr.x; acc[2][1] += x2.F * wr.y; acc[2][2] += x2.F * wr.z; acc[2][3] += x2.F * wr.w; \
                acc[3][0] += x3.F * wr.x; acc[3][1] += x3.F * wr.y; acc[3][2] += x3.F * wr.z; acc[3][3] += x3.F * wr.w; }
            KSTEP(0, x)
            KSTEP(1, y)
            KSTEP(2, z)
            KSTEP(3, w)
            #undef KSTEP
        }
        __syncthreads();
    }
    #pragma unroll
    for (int i = 0; i < 4; i++) {
        int gn = node0 + n0 + i;
        if (gn < nRows) {
            float sc = dinv[gn];
            store_h4(&out[(size_t)gn * 64 + c0],
                     make_float4(acc[i][0] * sc, acc[i][1] * sc, acc[i][2] * sc, acc[i][3] * sc));
        }
    }
}

// out[n,c] = relu( dinv[n] * ( sum_{e: dst=n} hd[src,c] + hd[n,c] ) + bias[c] )  — fp16 rows
// Quad q owns a CONTIGUOUS quarter of the edge list; 4 edges/iter: 4 independent
// index loads then 4 independent row gathers — chain depth 2 regardless of degree.
__global__ __launch_bounds__(256) void agg_kernel(const __half* __restrict__ hd, const int* __restrict__ offs,
                                                  const int* __restrict__ csr_src,
                                                  const float* __restrict__ dinv, const float* __restrict__ bias,
                                                  __half* __restrict__ out) {
    int lane = threadIdx.x & 63;
    int node = blockIdx.x * 4 + (threadIdx.x >> 6);
    if (node >= N_NODES) return;
    int q = lane >> 4;
    int cc = (lane & 15) * 4;
    float4 acc = make_float4(0.f, 0.f, 0.f, 0.f);
    int beg = offs[node], end = offs[node + 1];
    int deg = end - beg;
    int chunk = (deg + 3) >> 2;
    int jb = beg + q * chunk;
    int je = jb + chunk < end ? jb + chunk : end;
    int j = jb;
    for (; j + 4 <= je; j += 4) {
        int s0 = csr_src[j + 0];
        int s1 = csr_src[j + 1];
        int s2 = csr_src[j + 2];
        int s3 = csr_src[j + 3];
        float4 h0 = load_h4(&hd[(size_t)s0 * 64 + cc]);
        float4 h1 = load_h4(&hd[(size_t)s1 * 64 + cc]);
        float4 h2 = load_h4(&hd[(size_t)s2 * 64 + cc]);
        float4 h3 = load_h4(&hd[(size_t)s3 * 64 + cc]);
        acc.x += (h0.x + h1.x) + (h2.x + h3.x);
        acc.y += (h0.y + h1.y) + (h2.y + h3.y);
        acc.z += (h0.z + h1.z) + (h2.z + h3.z);
        acc.w += (h0.w + h1.w) + (h2.w + h3.w);
    }
    for (; j < je; j++) {
        int s = csr_src[j];
        float4 hv = load_h4(&hd[(size_t)s * 64 + cc]);
        acc.x += hv.x; acc.y += hv.y; acc.z += hv.z; acc.w += hv.w;
    }
    #pragma unroll
    for (int m = 16; m <= 32; m <<= 1) {
        acc.x += __shfl_xor(acc.x, m, 64);
        acc.y += __shfl_xor(acc.y, m, 64);
        acc.z += __shfl_xor(acc.z, m, 64);
        acc.w += __shfl_xor(acc.w, m, 64);
    }
    if (q == 0) {
        float di = dinv[node];
        float4 hn = load_h4(&hd[(size_t)node * 64 + cc]);
        const float4 bv = *(const float4*)&bias[cc];
        float4 r;
        r.x = fmaxf(fmaf(di, acc.x + hn.x, bv.x), 0.0f);
        r.y = fmaxf(fmaf(di, acc.y + hn.y, bv.y), 0.0f);
        r.z = fmaxf(fmaf(di, acc.z + hn.z, bv.z), 0.0f);
        r.w = fmaxf(fmaf(di, acc.w + hn.w, bv.w), 0.0f);
        store_h4(&out[(size_t)node * 64 + cc], r);
    }
}

__global__ __launch_bounds__(256) void pool_kernel(const __half* __restrict__ y, const int* __restrict__ batch,
                                                   const float* __restrict__ Wlin,
                                                   float* __restrict__ gpart) {
    __shared__ float lsum[NUM_GRAPHS];
    __shared__ float lcnt[NUM_GRAPHS];
    int tid = threadIdx.x;
    if (tid < NUM_GRAPHS) { lsum[tid] = 0.0f; lcnt[tid] = 0.0f; }
    __syncthreads();
    int lane = tid & 63, wid = tid >> 6;
    int q = lane >> 4;
    int l16 = lane & 15;
    int cc = l16 * 4;
    float4 wl = *(const float4*)&Wlin[cc];
    int stride = gridDim.x * 16;
    #pragma unroll 2
    for (int node = blockIdx.x * 16 + wid * 4 + q; node < N_NODES; node += stride) {
        float4 v = load_h4(&y[(size_t)node * 64 + cc]);
        float d = v.x * wl.x + v.y * wl.y + v.z * wl.z + v.w * wl.w;
        #pragma unroll
        for (int m = 1; m < 16; m <<= 1) d += __shfl_xor(d, m, 64);
        if (l16 == 0) {
            int g = batch[node];
            atomicAdd(&lsum[g], d);
            atomicAdd(&lcnt[g], 1.0f);
        }
    }
    __syncthreads();
    if (tid < NUM_GRAPHS) {
        gpart[(size_t)blockIdx.x * (2 * NUM_GRAPHS) + tid] = lsum[tid];
        gpart[(size_t)blockIdx.x * (2 * NUM_GRAPHS) + NUM_GRAPHS + tid] = lcnt[tid];
    }
}

__global__ __launch_bounds__(1024) void final_kernel(const float* __restrict__ gpart, const float* __restrict__ blin,
                                                     float* __restrict__ out) {
    __shared__ float rs[1024];
    __shared__ float rc[1024];
    int tid = threadIdx.x;
    int g = tid & 63;
    int c = tid >> 6;
    float s = 0.0f, cn = 0.0f;
    for (int b = c; b < POOL_BLOCKS; b += 16) {
        s  += gpart[(size_t)b * (2 * NUM_GRAPHS) + g];
        cn += gpart[(size_t)b * (2 * NUM_GRAPHS) + NUM_GRAPHS + g];
    }
    rs[tid] = s; rc[tid] = cn;
    __syncthreads();
    if (c == 0) {
        float ts = 0.0f, tc = 0.0f;
        #pragma unroll
        for (int k = 0; k < 16; k++) { ts += rs[k * 64 + g]; tc += rc[k * 64 + g]; }
        out[g] = ts / fmaxf(tc, 1.0f) + blin[0];
    }
}

extern "C" void kernel_launch(void* const* d_in, const int* in_sizes, int n_in,
                              void* d_out, int out_size, void* d_ws, size_t ws_size,
                              hipStream_t stream) {
    const float* x    = (const float*)d_in[0];
    const int*   ei   = (const int*)d_in[1];
    const int*   batch= (const int*)d_in[2];
    const float* W1   = (const float*)d_in[3];
    const float* b1   = (const float*)d_in[4];
    const float* W2   = (const float*)d_in[5];
    const float* b2   = (const float*)d_in[6];
    const float* Wlin = (const float*)d_in[7];
    const float* blin = (const float*)d_in[8];
    float* out = (float*)d_out;
    const int* srcA = ei;
    const int* dstA = ei + N_EDGES;

    char* p = (char*)d_ws;
    auto alloc = [&](size_t n) { char* r = p; p += (n + 255) & ~(size_t)255; return r; };
    int*    hist_g  = (int*)alloc((size_t)NB * NBLK * 4);
    int*    pos     = (int*)alloc((size_t)NB * NBLK * 4);
    int*    offs    = (int*)alloc((size_t)(N_NODES + 1) * 4);
    int*    binned  = (int*)alloc((size_t)N_EDGES * 4);
    int*    csr_src = (int*)alloc((size_t)N_EDGES * 4);
    float*  dinv    = (float*)alloc((size_t)N_NODES * 4);
    float*  gpart   = (float*)alloc((size_t)POOL_BLOCKS * 2 * NUM_GRAPHS * 4);
    __half* bufA    = (__half*)alloc((size_t)N_NODES * 64 * 2);
    __half* bufB    = (__half*)alloc((size_t)N_NODES * 64 * 2);
    // no memset needed: every buffer is fully written before read

    hist_kernel<<<NBLK, 256, 0, stream>>>(dstA, hist_g);
    scan2_kernel<<<1, 1024, 0, stream>>>(hist_g, pos, offs);
    bin_kernel<<<NBLK, 256, 0, stream>>>(srcA, dstA, pos, binned);
    build_kernel<<<NB, 256, 0, stream>>>(binned, pos, offs, dinv, csr_src);

    gemm_kernel<IN_DIM, float><<<(N_NODES + 63) / 64, 256, 0, stream>>>(x, W1, dinv, bufA, N_NODES);
    agg_kernel<<<(N_NODES + 3) / 4, 256, 0, stream>>>(bufA, offs, csr_src, dinv, b1, bufB);
    gemm_kernel<HID, __half><<<(N_NODES + 63) / 64, 256, 0, stream>>>(bufB, W2, dinv, bufA, N_NODES);
    agg_kernel<<<(N_NODES + 3) / 4, 256, 0, stream>>>(bufA, offs, csr_src, dinv, b2, bufB);

    pool_kernel<<<POOL_BLOCKS, 256, 0, stream>>>(bufB, batch, Wlin, gpart);
    final_kernel<<<1, 1024, 0, stream>>>(gpart, blin, out);
}

// Round 14
// 210.438 us; speedup vs baseline: 1.0433x; 1.0433x over previous
//
#include <hip/hip_runtime.h>
#include <hip/hip_fp16.h>

#define N_NODES 50000
#define N_EDGES 800000
#define IN_DIM 128
#define HID 64
#define NUM_GRAPHS 64
#define RED_BLOCKS 128
#define NB 196        // buckets: dst >> 8 (256 node-ids per bucket)
#define NBLK 256      // blocks in hist/bin passes (edge->block map must match)

__device__ inline float4 load_h4(const __half* p) {
    const __half2* q = (const __half2*)p;
    float2 a = __half22float2(q[0]);
    float2 b = __half22float2(q[1]);
    return make_float4(a.x, a.y, b.x, b.y);
}
__device__ inline void store_h4(__half* p, float4 v) {
    __half2* q = (__half2*)p;
    q[0] = __floats2half2_rn(v.x, v.y);
    q[1] = __floats2half2_rn(v.z, v.w);
}

// Pass 1: per-block LDS histogram over NB buckets. hist_g[b*NBLK + blk] = count.
__global__ __launch_bounds__(256) void hist_kernel(const int* __restrict__ dst, int* __restrict__ hist_g) {
    __shared__ int h[NB];
    int tid = threadIdx.x;
    for (int i = tid; i < NB; i += 256) h[i] = 0;
    __syncthreads();
    const int NI = N_EDGES / 4;
    for (int i = blockIdx.x * 256 + tid; i < NI; i += NBLK * 256) {
        int4 d = ((const int4*)dst)[i];
        atomicAdd(&h[d.x >> 8], 1);
        atomicAdd(&h[d.y >> 8], 1);
        atomicAdd(&h[d.z >> 8], 1);
        atomicAdd(&h[d.w >> 8], 1);
    }
    __syncthreads();
    for (int i = tid; i < NB; i += 256) hist_g[i * NBLK + blockIdx.x] = h[i];
}

// Pass 2: single-block exclusive scan of hist_g (bucket-major, L = NB*NBLK ints).
__global__ __launch_bounds__(1024) void scan2_kernel(const int* __restrict__ in, int* __restrict__ pos,
                                                     int* __restrict__ offs) {
    __shared__ int wsum[16];
    __shared__ int tot_s;
    int tid = threadIdx.x;
    int lane = tid & 63, wid = tid >> 6;
    int carry = 0;
    const int L = NB * NBLK;                   // 50176, divisible by 4
    for (int base = 0; base < L; base += 4096) {
        int idx = base + tid * 4;
        int v0 = 0, v1 = 0, v2 = 0, v3 = 0;
        if (idx < L) { int4 v = *(const int4*)&in[idx]; v0 = v.x; v1 = v.y; v2 = v.z; v3 = v.w; }
        int s0 = v0, s1 = s0 + v1, s2 = s1 + v2, s3 = s2 + v3;
        int inc = s3;
        #pragma unroll
        for (int d = 1; d < 64; d <<= 1) { int t = __shfl_up(inc, d, 64); if (lane >= d) inc += t; }
        if (lane == 63) wsum[wid] = inc;
        __syncthreads();
        if (tid < 16) {
            int wv = wsum[tid], winc = wv;
            #pragma unroll
            for (int d = 1; d < 16; d <<= 1) { int t = __shfl_up(winc, d, 16); if (tid >= d) winc += t; }
            wsum[tid] = winc - wv;
            if (tid == 15) tot_s = winc;
        }
        __syncthreads();
        int excl = carry + wsum[wid] + inc - s3;
        if (idx < L) { int4 o; o.x = excl; o.y = excl + s0; o.z = excl + s1; o.w = excl + s2; *(int4*)&pos[idx] = o; }
        carry += tot_s;
    }
    if (tid == 0) offs[N_NODES] = N_EDGES;
}

// Pass 3: bin edges bucket-major, packed 4B: src(16b) | (dst&255)<<16.
__global__ __launch_bounds__(256) void bin_kernel(const int* __restrict__ src, const int* __restrict__ dst,
                                                  const int* __restrict__ pos, int* __restrict__ binned) {
    __shared__ int cur[NB];
    int tid = threadIdx.x;
    for (int i = tid; i < NB; i += 256) cur[i] = pos[i * NBLK + blockIdx.x];
    __syncthreads();
    const int NI = N_EDGES / 4;
    for (int i = blockIdx.x * 256 + tid; i < NI; i += NBLK * 256) {
        int4 s = ((const int4*)src)[i];
        int4 d = ((const int4*)dst)[i];
        int p0 = atomicAdd(&cur[d.x >> 8], 1); binned[p0] = (s.x & 0xFFFF) | ((d.x & 255) << 16);
        int p1 = atomicAdd(&cur[d.y >> 8], 1); binned[p1] = (s.y & 0xFFFF) | ((d.y & 255) << 16);
        int p2 = atomicAdd(&cur[d.z >> 8], 1); binned[p2] = (s.z & 0xFFFF) | ((d.z & 255) << 16);
        int p3 = atomicAdd(&cur[d.w >> 8], 1); binned[p3] = (s.w & 0xFFFF) | ((d.w & 255) << 16);
    }
}

// Pass 4: one block per bucket — LDS counting sort by local id; writes offs, dinv, csr_src.
__global__ __launch_bounds__(256) void build_kernel(const int* __restrict__ binned, const int* __restrict__ pos,
                                                    int* __restrict__ offs, float* __restrict__ dinv,
                                                    int* __restrict__ csr_src) {
    __shared__ int cnt[256];
    __shared__ int excl[256];
    __shared__ int rnk[256];
    __shared__ int wtot[4];
    int b = blockIdx.x, tid = threadIdx.x;
    int base = pos[b * NBLK];
    int end  = (b == NB - 1) ? N_EDGES : pos[(b + 1) * NBLK];
    cnt[tid] = 0; rnk[tid] = 0;
    __syncthreads();
    for (int j = base + tid; j < end; j += 256) atomicAdd(&cnt[(binned[j] >> 16) & 255], 1);
    __syncthreads();
    int v = cnt[tid];
    int lane = tid & 63, wid = tid >> 6;
    int inc = v;
    #pragma unroll
    for (int d = 1; d < 64; d <<= 1) { int t = __shfl_up(inc, d, 64); if (lane >= d) inc += t; }
    if (lane == 63) wtot[wid] = inc;
    __syncthreads();
    if (tid == 0) {
        int a = 0;
        for (int w = 0; w < 4; w++) { int t = wtot[w]; wtot[w] = a; a += t; }
    }
    __syncthreads();
    excl[tid] = wtot[wid] + inc - v;
    int node = b * 256 + tid;
    if (node < N_NODES) {
        offs[node] = base + excl[tid];
        dinv[node] = rsqrtf((float)v + 1.0f);
    }
    __syncthreads();
    for (int j = base + tid; j < end; j += 256) {
        int e = binned[j];
        int l = (e >> 16) & 255;
        int r = atomicAdd(&rnk[l], 1);
        csr_src[base + excl[l] + r] = e & 0xFFFF;
    }
}

// C = (A[nRows,K] @ W[K,64]) * dinv[n] -> fp16.
// Block: 64 nodes x 64 cols; thread = 4 nodes x 4 contiguous cols. [round-12 proven shape]
template <int K, typename TIN>
__global__ __launch_bounds__(256) void gemm_kernel(const TIN* __restrict__ A, const float* __restrict__ W,
                                                   const float* __restrict__ dinv,
                                                   __half* __restrict__ out, int nRows) {
    constexpr int KB = 64;
    constexpr int KBP = KB + 4;               // 68
    __shared__ float xs[64 * KBP];
    __shared__ float ws[KB * 68];
    int tid = threadIdx.x;
    int node0 = blockIdx.x * 64;
    int c0 = (tid & 15) * 4, n0 = (tid >> 4) * 4;
    float acc[4][4] = {};
    for (int kb = 0; kb < K; kb += KB) {
        for (int i = tid; i < KB * 16; i += 256) {
            int k = i >> 4, c4 = (i & 15) * 4;
            *(float4*)&ws[k * 68 + c4] = *(const float4*)&W[(size_t)(kb + k) * 64 + c4];
        }
        for (int i = tid; i < 64 * (KB / 4); i += 256) {
            int n = i / (KB / 4), k4 = (i % (KB / 4)) * 4;
            int gn = node0 + n;
            float4 v;
            if (gn < nRows) {
                if constexpr (sizeof(TIN) == 4) v = *(const float4*)&A[(size_t)gn * K + kb + k4];
                else                            v = load_h4((const __half*)&A[(size_t)gn * K + kb + k4]);
            } else v = make_float4(0.f, 0.f, 0.f, 0.f);
            *(float4*)&xs[n * KBP + k4] = v;
        }
        __syncthreads();
        for (int k = 0; k < KB; k += 4) {
            float4 x0 = *(const float4*)&xs[(n0 + 0) * KBP + k];
            float4 x1 = *(const float4*)&xs[(n0 + 1) * KBP + k];
            float4 x2 = *(const float4*)&xs[(n0 + 2) * KBP + k];
            float4 x3 = *(const float4*)&xs[(n0 + 3) * KBP + k];
            #define KSTEP(KK, F) { \
                float4 wr = *(const float4*)&ws[(k + KK) * 68 + c0]; \
                acc[0][0] += x0.F * wr.x; acc[0][1] += x0.F * wr.y; acc[0][2] += x0.F * wr.z; acc[0][3] += x0.F * wr.w; \
                acc[1][0] += x1.F * wr.x; acc[1][1] += x1.F * wr.y; acc[1][2] += x1.F * wr.z; acc[1][3] += x1.F * wr.w; \
                acc[2][0] += x2.F * wr.x; acc[2][1] += x2.F * wr.y; acc[2][2] += x2.F * wr.z; acc[2][3] += x2.F * wr.w; \
                acc[3][0] += x3.F * wr.x; acc[3][1] += x3.F * wr.y; acc[3][2] += x3.F * wr.z; acc[3][3] += x3.F * wr.w; }
            KSTEP(0, x)
            KSTEP(1, y)
            KSTEP(2, z)
            KSTEP(3, w)
            #undef KSTEP
        }
        __syncthreads();
    }
    #pragma unroll
    for (int i = 0; i < 4; i++) {
        int gn = node0 + n0 + i;
        if (gn < nRows) {
            float sc = dinv[gn];
            store_h4(&out[(size_t)gn * 64 + c0],
                     make_float4(acc[i][0] * sc, acc[i][1] * sc, acc[i][2] * sc, acc[i][3] * sc));
        }
    }
}

// out[n,c] = relu( dinv[n] * ( sum_{e: dst=n} hd[src,c] + hd[n,c] ) + bias[c] )
// [round-12 proven interleaved edge loop: quad q walks j=beg+q step 4]
__global__ __launch_bounds__(256) void agg_kernel(const __half* __restrict__ hd, const int* __restrict__ offs,
                                                  const int* __restrict__ csr_src,
                                                  const float* __restrict__ dinv, const float* __restrict__ bias,
                                                  __half* __restrict__ out) {
    int lane = threadIdx.x & 63;
    int node = blockIdx.x * 4 + (threadIdx.x >> 6);
    if (node >= N_NODES) return;
    int q = lane >> 4;
    int cc = (lane & 15) * 4;
    float4 acc = make_float4(0.f, 0.f, 0.f, 0.f);
    int beg = offs[node], end = offs[node + 1];
    #pragma unroll 2
    for (int j = beg + q; j < end; j += 4) {
        int s = csr_src[j];
        float4 hv = load_h4(&hd[(size_t)s * 64 + cc]);
        acc.x += hv.x; acc.y += hv.y; acc.z += hv.z; acc.w += hv.w;
    }
    #pragma unroll
    for (int m = 16; m <= 32; m <<= 1) {
        acc.x += __shfl_xor(acc.x, m, 64);
        acc.y += __shfl_xor(acc.y, m, 64);
        acc.z += __shfl_xor(acc.z, m, 64);
        acc.w += __shfl_xor(acc.w, m, 64);
    }
    if (q == 0) {
        float di = dinv[node];
        float4 hn = load_h4(&hd[(size_t)node * 64 + cc]);
        const float4 bv = *(const float4*)&bias[cc];
        float4 r;
        r.x = fmaxf(fmaf(di, acc.x + hn.x, bv.x), 0.0f);
        r.y = fmaxf(fmaf(di, acc.y + hn.y, bv.y), 0.0f);
        r.z = fmaxf(fmaf(di, acc.z + hn.z, bv.z), 0.0f);
        r.w = fmaxf(fmaf(di, acc.w + hn.w, bv.w), 0.0f);
        store_h4(&out[(size_t)node * 64 + cc], r);
    }
}

// Layer-2 agg with fused Wlin dot epilogue: writes per-node scalar ndot (fp32, pre-rounding).
__global__ __launch_bounds__(256) void agg2dot_kernel(const __half* __restrict__ hd, const int* __restrict__ offs,
                                                      const int* __restrict__ csr_src,
                                                      const float* __restrict__ dinv, const float* __restrict__ bias,
                                                      const float* __restrict__ Wlin,
                                                      float* __restrict__ ndot) {
    int lane = threadIdx.x & 63;
    int node = blockIdx.x * 4 + (threadIdx.x >> 6);
    if (node >= N_NODES) return;
    int q = lane >> 4;
    int cc = (lane & 15) * 4;
    float4 acc = make_float4(0.f, 0.f, 0.f, 0.f);
    int beg = offs[node], end = offs[node + 1];
    #pragma unroll 2
    for (int j = beg + q; j < end; j += 4) {
        int s = csr_src[j];
        float4 hv = load_h4(&hd[(size_t)s * 64 + cc]);
        acc.x += hv.x; acc.y += hv.y; acc.z += hv.z; acc.w += hv.w;
    }
    #pragma unroll
    for (int m = 16; m <= 32; m <<= 1) {
        acc.x += __shfl_xor(acc.x, m, 64);
        acc.y += __shfl_xor(acc.y, m, 64);
        acc.z += __shfl_xor(acc.z, m, 64);
        acc.w += __shfl_xor(acc.w, m, 64);
    }
    if (q == 0) {
        float di = dinv[node];
        float4 hn = load_h4(&hd[(size_t)node * 64 + cc]);
        const float4 bv = *(const float4*)&bias[cc];
        const float4 wl = *(const float4*)&Wlin[cc];
        float rx = fmaxf(fmaf(di, acc.x + hn.x, bv.x), 0.0f);
        float ry = fmaxf(fmaf(di, acc.y + hn.y, bv.y), 0.0f);
        float rz = fmaxf(fmaf(di, acc.z + hn.z, bv.z), 0.0f);
        float rw = fmaxf(fmaf(di, acc.w + hn.w, bv.w), 0.0f);
        float d = rx * wl.x + ry * wl.y + rz * wl.z + rw * wl.w;
        #pragma unroll
        for (int m = 1; m < 16; m <<= 1) d += __shfl_xor(d, m, 64);
        if ((lane & 15) == 0) ndot[node] = d;
    }
}

// Segment-reduce ndot by batch into per-block partials (coalesced reads, LDS atomics).
__global__ __launch_bounds__(256) void reduce_kernel(const float* __restrict__ ndot, const int* __restrict__ batch,
                                                     float* __restrict__ gpart) {
    __shared__ float lsum[NUM_GRAPHS];
    __shared__ float lcnt[NUM_GRAPHS];
    int tid = threadIdx.x;
    if (tid < NUM_GRAPHS) { lsum[tid] = 0.0f; lcnt[tid] = 0.0f; }
    __syncthreads();
    for (int i = blockIdx.x * 256 + tid; i < N_NODES; i += RED_BLOCKS * 256) {
        atomicAdd(&lsum[batch[i]], ndot[i]);
        atomicAdd(&lcnt[batch[i]], 1.0f);
    }
    __syncthreads();
    if (tid < NUM_GRAPHS) {
        gpart[(size_t)blockIdx.x * (2 * NUM_GRAPHS) + tid] = lsum[tid];
        gpart[(size_t)blockIdx.x * (2 * NUM_GRAPHS) + NUM_GRAPHS + tid] = lcnt[tid];
    }
}

__global__ __launch_bounds__(1024) void final_kernel(const float* __restrict__ gpart, const float* __restrict__ blin,
                                                     float* __restrict__ out) {
    __shared__ float rs[1024];
    __shared__ float rc[1024];
    int tid = threadIdx.x;
    int g = tid & 63;
    int c = tid >> 6;
    float s = 0.0f, cn = 0.0f;
    for (int b = c; b < RED_BLOCKS; b += 16) {
        s  += gpart[(size_t)b * (2 * NUM_GRAPHS) + g];
        cn += gpart[(size_t)b * (2 * NUM_GRAPHS) + NUM_GRAPHS + g];
    }
    rs[tid] = s; rc[tid] = cn;
    __syncthreads();
    if (c == 0) {
        float ts = 0.0f, tc = 0.0f;
        #pragma unroll
        for (int k = 0; k < 16; k++) { ts += rs[k * 64 + g]; tc += rc[k * 64 + g]; }
        out[g] = ts / fmaxf(tc, 1.0f) + blin[0];
    }
}

extern "C" void kernel_launch(void* const* d_in, const int* in_sizes, int n_in,
                              void* d_out, int out_size, void* d_ws, size_t ws_size,
                              hipStream_t stream) {
    const float* x    = (const float*)d_in[0];
    const int*   ei   = (const int*)d_in[1];
    const int*   batch= (const int*)d_in[2];
    const float* W1   = (const float*)d_in[3];
    const float* b1   = (const float*)d_in[4];
    const float* W2   = (const float*)d_in[5];
    const float* b2   = (const float*)d_in[6];
    const float* Wlin = (const float*)d_in[7];
    const float* blin = (const float*)d_in[8];
    float* out = (float*)d_out;
    const int* srcA = ei;
    const int* dstA = ei + N_EDGES;

    char* p = (char*)d_ws;
    auto alloc = [&](size_t n) { char* r = p; p += (n + 255) & ~(size_t)255; return r; };
    int*    hist_g  = (int*)alloc((size_t)NB * NBLK * 4);
    int*    pos     = (int*)alloc((size_t)NB * NBLK * 4);
    int*    offs    = (int*)alloc((size_t)(N_NODES + 1) * 4);
    int*    binned  = (int*)alloc((size_t)N_EDGES * 4);
    int*    csr_src = (int*)alloc((size_t)N_EDGES * 4);
    float*  dinv    = (float*)alloc((size_t)N_NODES * 4);
    float*  ndot    = (float*)alloc((size_t)N_NODES * 4);
    float*  gpart   = (float*)alloc((size_t)RED_BLOCKS * 2 * NUM_GRAPHS * 4);
    __half* bufA    = (__half*)alloc((size_t)N_NODES * 64 * 2);
    __half* bufB    = (__half*)alloc((size_t)N_NODES * 64 * 2);
    // no memset needed: every buffer is fully written before read

    hist_kernel<<<NBLK, 256, 0, stream>>>(dstA, hist_g);
    scan2_kernel<<<1, 1024, 0, stream>>>(hist_g, pos, offs);
    bin_kernel<<<NBLK, 256, 0, stream>>>(srcA, dstA, pos, binned);
    build_kernel<<<NB, 256, 0, stream>>>(binned, pos, offs, dinv, csr_src);

    gemm_kernel<IN_DIM, float><<<(N_NODES + 63) / 64, 256, 0, stream>>>(x, W1, dinv, bufA, N_NODES);
    agg_kernel<<<(N_NODES + 3) / 4, 256, 0, stream>>>(bufA, offs, csr_src, dinv, b1, bufB);
    gemm_kernel<HID, __half><<<(N_NODES + 63) / 64, 256, 0, stream>>>(bufB, W2, dinv, bufA, N_NODES);
    agg2dot_kernel<<<(N_NODES + 3) / 4, 256, 0, stream>>>(bufA, offs, csr_src, dinv, b2, Wlin, ndot);

    reduce_kernel<<<RED_BLOCKS, 256, 0, stream>>>(ndot, batch, gpart);
    final_kernel<<<1, 1024, 0, stream>>>(gpart, blin, out);
}

// Round 15
// 209.421 us; speedup vs baseline: 1.0484x; 1.0049x over previous
//
#include <hip/hip_runtime.h>
#include <hip/hip_fp16.h>

#define N_NODES 50000
#define N_EDGES 800000
#define IN_DIM 128
#define HID 64
#define NUM_GRAPHS 64
#define NB 196        // buckets: dst >> 8 (256 node-ids per bucket)
#define NBLK 256      // blocks in hist/bin passes (edge->block map must match)

__device__ inline float4 load_h4(const __half* p) {
    const __half2* q = (const __half2*)p;
    float2 a = __half22float2(q[0]);
    float2 b = __half22float2(q[1]);
    return make_float4(a.x, a.y, b.x, b.y);
}
__device__ inline void store_h4(__half* p, float4 v) {
    __half2* q = (__half2*)p;
    q[0] = __floats2half2_rn(v.x, v.y);
    q[1] = __floats2half2_rn(v.z, v.w);
}

// Pass 1: per-block LDS histogram over NB buckets. hist_g[b*NBLK + blk] = count.
__global__ __launch_bounds__(256) void hist_kernel(const int* __restrict__ dst, int* __restrict__ hist_g) {
    __shared__ int h[NB];
    int tid = threadIdx.x;
    for (int i = tid; i < NB; i += 256) h[i] = 0;
    __syncthreads();
    const int NI = N_EDGES / 4;
    for (int i = blockIdx.x * 256 + tid; i < NI; i += NBLK * 256) {
        int4 d = ((const int4*)dst)[i];
        atomicAdd(&h[d.x >> 8], 1);
        atomicAdd(&h[d.y >> 8], 1);
        atomicAdd(&h[d.z >> 8], 1);
        atomicAdd(&h[d.w >> 8], 1);
    }
    __syncthreads();
    for (int i = tid; i < NB; i += 256) hist_g[i * NBLK + blockIdx.x] = h[i];
}

// Pass 2: single-block exclusive scan of hist_g (bucket-major, L = NB*NBLK ints).
__global__ __launch_bounds__(1024) void scan2_kernel(const int* __restrict__ in, int* __restrict__ pos,
                                                     int* __restrict__ offs) {
    __shared__ int wsum[16];
    __shared__ int tot_s;
    int tid = threadIdx.x;
    int lane = tid & 63, wid = tid >> 6;
    int carry = 0;
    const int L = NB * NBLK;                   // 50176, divisible by 4
    for (int base = 0; base < L; base += 4096) {
        int idx = base + tid * 4;
        int v0 = 0, v1 = 0, v2 = 0, v3 = 0;
        if (idx < L) { int4 v = *(const int4*)&in[idx]; v0 = v.x; v1 = v.y; v2 = v.z; v3 = v.w; }
        int s0 = v0, s1 = s0 + v1, s2 = s1 + v2, s3 = s2 + v3;
        int inc = s3;
        #pragma unroll
        for (int d = 1; d < 64; d <<= 1) { int t = __shfl_up(inc, d, 64); if (lane >= d) inc += t; }
        if (lane == 63) wsum[wid] = inc;
        __syncthreads();
        if (tid < 16) {
            int wv = wsum[tid], winc = wv;
            #pragma unroll
            for (int d = 1; d < 16; d <<= 1) { int t = __shfl_up(winc, d, 16); if (tid >= d) winc += t; }
            wsum[tid] = winc - wv;
            if (tid == 15) tot_s = winc;
        }
        __syncthreads();
        int excl = carry + wsum[wid] + inc - s3;
        if (idx < L) { int4 o; o.x = excl; o.y = excl + s0; o.z = excl + s1; o.w = excl + s2; *(int4*)&pos[idx] = o; }
        carry += tot_s;
    }
    if (tid == 0) offs[N_NODES] = N_EDGES;
}

// Pass 3: bin edges bucket-major, packed 4B: src(16b) | (dst&255)<<16.
__global__ __launch_bounds__(256) void bin_kernel(const int* __restrict__ src, const int* __restrict__ dst,
                                                  const int* __restrict__ pos, int* __restrict__ binned) {
    __shared__ int cur[NB];
    int tid = threadIdx.x;
    for (int i = tid; i < NB; i += 256) cur[i] = pos[i * NBLK + blockIdx.x];
    __syncthreads();
    const int NI = N_EDGES / 4;
    for (int i = blockIdx.x * 256 + tid; i < NI; i += NBLK * 256) {
        int4 s = ((const int4*)src)[i];
        int4 d = ((const int4*)dst)[i];
        int p0 = atomicAdd(&cur[d.x >> 8], 1); binned[p0] = (s.x & 0xFFFF) | ((d.x & 255) << 16);
        int p1 = atomicAdd(&cur[d.y >> 8], 1); binned[p1] = (s.y & 0xFFFF) | ((d.y & 255) << 16);
        int p2 = atomicAdd(&cur[d.z >> 8], 1); binned[p2] = (s.z & 0xFFFF) | ((d.z & 255) << 16);
        int p3 = atomicAdd(&cur[d.w >> 8], 1); binned[p3] = (s.w & 0xFFFF) | ((d.w & 255) << 16);
    }
}

// Pass 4: one block per bucket — LDS counting sort by local id; writes offs, dinv, csr_src.
__global__ __launch_bounds__(256) void build_kernel(const int* __restrict__ binned, const int* __restrict__ pos,
                                                    int* __restrict__ offs, float* __restrict__ dinv,
                                                    int* __restrict__ csr_src) {
    __shared__ int cnt[256];
    __shared__ int excl[256];
    __shared__ int rnk[256];
    __shared__ int wtot[4];
    int b = blockIdx.x, tid = threadIdx.x;
    int base = pos[b * NBLK];
    int end  = (b == NB - 1) ? N_EDGES : pos[(b + 1) * NBLK];
    cnt[tid] = 0; rnk[tid] = 0;
    __syncthreads();
    for (int j = base + tid; j < end; j += 256) atomicAdd(&cnt[(binned[j] >> 16) & 255], 1);
    __syncthreads();
    int v = cnt[tid];
    int lane = tid & 63, wid = tid >> 6;
    int inc = v;
    #pragma unroll
    for (int d = 1; d < 64; d <<= 1) { int t = __shfl_up(inc, d, 64); if (lane >= d) inc += t; }
    if (lane == 63) wtot[wid] = inc;
    __syncthreads();
    if (tid == 0) {
        int a = 0;
        for (int w = 0; w < 4; w++) { int t = wtot[w]; wtot[w] = a; a += t; }
    }
    __syncthreads();
    excl[tid] = wtot[wid] + inc - v;
    int node = b * 256 + tid;
    if (node < N_NODES) {
        offs[node] = base + excl[tid];
        dinv[node] = rsqrtf((float)v + 1.0f);
    }
    __syncthreads();
    for (int j = base + tid; j < end; j += 256) {
        int e = binned[j];
        int l = (e >> 16) & 255;
        int r = atomicAdd(&rnk[l], 1);
        csr_src[base + excl[l] + r] = e & 0xFFFF;
    }
}

// C = (A[nRows,K] @ W[K,64]) * dinv[n] -> fp16.
// Block: 64 nodes x 64 cols; thread = 4 nodes x 4 contiguous cols. [round-12 proven shape]
template <int K, typename TIN>
__global__ __launch_bounds__(256) void gemm_kernel(const TIN* __restrict__ A, const float* __restrict__ W,
                                                   const float* __restrict__ dinv,
                                                   __half* __restrict__ out, int nRows) {
    constexpr int KB = 64;
    constexpr int KBP = KB + 4;               // 68
    __shared__ float xs[64 * KBP];
    __shared__ float ws[KB * 68];
    int tid = threadIdx.x;
    int node0 = blockIdx.x * 64;
    int c0 = (tid & 15) * 4, n0 = (tid >> 4) * 4;
    float acc[4][4] = {};
    for (int kb = 0; kb < K; kb += KB) {
        for (int i = tid; i < KB * 16; i += 256) {
            int k = i >> 4, c4 = (i & 15) * 4;
            *(float4*)&ws[k * 68 + c4] = *(const float4*)&W[(size_t)(kb + k) * 64 + c4];
        }
        for (int i = tid; i < 64 * (KB / 4); i += 256) {
            int n = i / (KB / 4), k4 = (i % (KB / 4)) * 4;
            int gn = node0 + n;
            float4 v;
            if (gn < nRows) {
                if constexpr (sizeof(TIN) == 4) v = *(const float4*)&A[(size_t)gn * K + kb + k4];
                else                            v = load_h4((const __half*)&A[(size_t)gn * K + kb + k4]);
            } else v = make_float4(0.f, 0.f, 0.f, 0.f);
            *(float4*)&xs[n * KBP + k4] = v;
        }
        __syncthreads();
        for (int k = 0; k < KB; k += 4) {
            float4 x0 = *(const float4*)&xs[(n0 + 0) * KBP + k];
            float4 x1 = *(const float4*)&xs[(n0 + 1) * KBP + k];
            float4 x2 = *(const float4*)&xs[(n0 + 2) * KBP + k];
            float4 x3 = *(const float4*)&xs[(n0 + 3) * KBP + k];
            #define KSTEP(KK, F) { \
                float4 wr = *(const float4*)&ws[(k + KK) * 68 + c0]; \
                acc[0][0] += x0.F * wr.x; acc[0][1] += x0.F * wr.y; acc[0][2] += x0.F * wr.z; acc[0][3] += x0.F * wr.w; \
                acc[1][0] += x1.F * wr.x; acc[1][1] += x1.F * wr.y; acc[1][2] += x1.F * wr.z; acc[1][3] += x1.F * wr.w; \
                acc[2][0] += x2.F * wr.x; acc[2][1] += x2.F * wr.y; acc[2][2] += x2.F * wr.z; acc[2][3] += x2.F * wr.w; \
                acc[3][0] += x3.F * wr.x; acc[3][1] += x3.F * wr.y; acc[3][2] += x3.F * wr.z; acc[3][3] += x3.F * wr.w; }
            KSTEP(0, x)
            KSTEP(1, y)
            KSTEP(2, z)
            KSTEP(3, w)
            #undef KSTEP
        }
        __syncthreads();
    }
    #pragma unroll
    for (int i = 0; i < 4; i++) {
        int gn = node0 + n0 + i;
        if (gn < nRows) {
            float sc = dinv[gn];
            store_h4(&out[(size_t)gn * 64 + c0],
                     make_float4(acc[i][0] * sc, acc[i][1] * sc, acc[i][2] * sc, acc[i][3] * sc));
        }
    }
}

// out[n,c] = relu( dinv[n] * ( sum_{e: dst=n} hd[src,c] + hd[n,c] ) + bias[c] )
// [round-12 proven interleaved edge loop: quad q walks j=beg+q step 4]
__global__ __launch_bounds__(256) void agg_kernel(const __half* __restrict__ hd, const int* __restrict__ offs,
                                                  const int* __restrict__ csr_src,
                                                  const float* __restrict__ dinv, const float* __restrict__ bias,
                                                  __half* __restrict__ out) {
    int lane = threadIdx.x & 63;
    int node = blockIdx.x * 4 + (threadIdx.x >> 6);
    if (node >= N_NODES) return;
    int q = lane >> 4;
    int cc = (lane & 15) * 4;
    float4 acc = make_float4(0.f, 0.f, 0.f, 0.f);
    int beg = offs[node], end = offs[node + 1];
    #pragma unroll 2
    for (int j = beg + q; j < end; j += 4) {
        int s = csr_src[j];
        float4 hv = load_h4(&hd[(size_t)s * 64 + cc]);
        acc.x += hv.x; acc.y += hv.y; acc.z += hv.z; acc.w += hv.w;
    }
    #pragma unroll
    for (int m = 16; m <= 32; m <<= 1) {
        acc.x += __shfl_xor(acc.x, m, 64);
        acc.y += __shfl_xor(acc.y, m, 64);
        acc.z += __shfl_xor(acc.z, m, 64);
        acc.w += __shfl_xor(acc.w, m, 64);
    }
    if (q == 0) {
        float di = dinv[node];
        float4 hn = load_h4(&hd[(size_t)node * 64 + cc]);
        const float4 bv = *(const float4*)&bias[cc];
        float4 r;
        r.x = fmaxf(fmaf(di, acc.x + hn.x, bv.x), 0.0f);
        r.y = fmaxf(fmaf(di, acc.y + hn.y, bv.y), 0.0f);
        r.z = fmaxf(fmaf(di, acc.z + hn.z, bv.z), 0.0f);
        r.w = fmaxf(fmaf(di, acc.w + hn.w, bv.w), 0.0f);
        store_h4(&out[(size_t)node * 64 + cc], r);
    }
}

// Layer-2 agg with fused Wlin dot epilogue: writes per-node scalar ndot (fp32, pre-rounding).
__global__ __launch_bounds__(256) void agg2dot_kernel(const __half* __restrict__ hd, const int* __restrict__ offs,
                                                      const int* __restrict__ csr_src,
                                                      const float* __restrict__ dinv, const float* __restrict__ bias,
                                                      const float* __restrict__ Wlin,
                                                      float* __restrict__ ndot) {
    int lane = threadIdx.x & 63;
    int node = blockIdx.x * 4 + (threadIdx.x >> 6);
    if (node >= N_NODES) return;
    int q = lane >> 4;
    int cc = (lane & 15) * 4;
    float4 acc = make_float4(0.f, 0.f, 0.f, 0.f);
    int beg = offs[node], end = offs[node + 1];
    #pragma unroll 2
    for (int j = beg + q; j < end; j += 4) {
        int s = csr_src[j];
        float4 hv = load_h4(&hd[(size_t)s * 64 + cc]);
        acc.x += hv.x; acc.y += hv.y; acc.z += hv.z; acc.w += hv.w;
    }
    #pragma unroll
    for (int m = 16; m <= 32; m <<= 1) {
        acc.x += __shfl_xor(acc.x, m, 64);
        acc.y += __shfl_xor(acc.y, m, 64);
        acc.z += __shfl_xor(acc.z, m, 64);
        acc.w += __shfl_xor(acc.w, m, 64);
    }
    if (q == 0) {
        float di = dinv[node];
        float4 hn = load_h4(&hd[(size_t)node * 64 + cc]);
        const float4 bv = *(const float4*)&bias[cc];
        const float4 wl = *(const float4*)&Wlin[cc];
        float rx = fmaxf(fmaf(di, acc.x + hn.x, bv.x), 0.0f);
        float ry = fmaxf(fmaf(di, acc.y + hn.y, bv.y), 0.0f);
        float rz = fmaxf(fmaf(di, acc.z + hn.z, bv.z), 0.0f);
        float rw = fmaxf(fmaf(di, acc.w + hn.w, bv.w), 0.0f);
        float d = rx * wl.x + ry * wl.y + rz * wl.z + rw * wl.w;
        #pragma unroll
        for (int m = 1; m < 16; m <<= 1) d += __shfl_xor(d, m, 64);
        if ((lane & 15) == 0) ndot[node] = d;
    }
}

// batch is SORTED: block g binary-searches its node range [lo, hi) and mean-reduces
// ndot over it directly into out[g]. One dispatch, no partials, no global atomics.
__global__ __launch_bounds__(256) void graphred_kernel(const float* __restrict__ ndot, const int* __restrict__ batch,
                                                       const float* __restrict__ blin, float* __restrict__ out) {
    __shared__ float wpart[4];
    int g = blockIdx.x;
    int tid = threadIdx.x;
    // lower_bound(batch, g) and lower_bound(batch, g+1)
    int lo = 0, hi = N_NODES;
    while (lo < hi) { int m = (lo + hi) >> 1; if (batch[m] < g) lo = m + 1; else hi = m; }
    int lo2 = lo, hi2 = N_NODES;
    while (lo2 < hi2) { int m = (lo2 + hi2) >> 1; if (batch[m] < g + 1) lo2 = m + 1; else hi2 = m; }
    float s = 0.0f;
    for (int i = lo + tid; i < lo2; i += 256) s += ndot[i];
    int lane = tid & 63, wid = tid >> 6;
    #pragma unroll
    for (int m = 32; m > 0; m >>= 1) s += __shfl_down(s, m, 64);
    if (lane == 0) wpart[wid] = s;
    __syncthreads();
    if (tid == 0) {
        float t = wpart[0] + wpart[1] + wpart[2] + wpart[3];
        float cnt = (float)(lo2 - lo);
        out[g] = t / fmaxf(cnt, 1.0f) + blin[0];
    }
}

extern "C" void kernel_launch(void* const* d_in, const int* in_sizes, int n_in,
                              void* d_out, int out_size, void* d_ws, size_t ws_size,
                              hipStream_t stream) {
    const float* x    = (const float*)d_in[0];
    const int*   ei   = (const int*)d_in[1];
    const int*   batch= (const int*)d_in[2];
    const float* W1   = (const float*)d_in[3];
    const float* b1   = (const float*)d_in[4];
    const float* W2   = (const float*)d_in[5];
    const float* b2   = (const float*)d_in[6];
    const float* Wlin = (const float*)d_in[7];
    const float* blin = (const float*)d_in[8];
    float* out = (float*)d_out;
    const int* srcA = ei;
    const int* dstA = ei + N_EDGES;

    char* p = (char*)d_ws;
    auto alloc = [&](size_t n) { char* r = p; p += (n + 255) & ~(size_t)255; return r; };
    int*    hist_g  = (int*)alloc((size_t)NB * NBLK * 4);
    int*    pos     = (int*)alloc((size_t)NB * NBLK * 4);
    int*    offs    = (int*)alloc((size_t)(N_NODES + 1) * 4);
    int*    binned  = (int*)alloc((size_t)N_EDGES * 4);
    int*    csr_src = (int*)alloc((size_t)N_EDGES * 4);
    float*  dinv    = (float*)alloc((size_t)N_NODES * 4);
    float*  ndot    = (float*)alloc((size_t)N_NODES * 4);
    __half* bufA    = (__half*)alloc((size_t)N_NODES * 64 * 2);
    __half* bufB    = (__half*)alloc((size_t)N_NODES * 64 * 2);
    // no memset needed: every buffer is fully written before read

    hist_kernel<<<NBLK, 256, 0, stream>>>(dstA, hist_g);
    scan2_kernel<<<1, 1024, 0, stream>>>(hist_g, pos, offs);
    bin_kernel<<<NBLK, 256, 0, stream>>>(srcA, dstA, pos, binned);
    build_kernel<<<NB, 256, 0, stream>>>(binned, pos, offs, dinv, csr_src);

    gemm_kernel<IN_DIM, float><<<(N_NODES + 63) / 64, 256, 0, stream>>>(x, W1, dinv, bufA, N_NODES);
    agg_kernel<<<(N_NODES + 3) / 4, 256, 0, stream>>>(bufA, offs, csr_src, dinv, b1, bufB);
    gemm_kernel<HID, __half><<<(N_NODES + 63) / 64, 256, 0, stream>>>(bufB, W2, dinv, bufA, N_NODES);
    agg2dot_kernel<<<(N_NODES + 3) / 4, 256, 0, stream>>>(bufA, offs, csr_src, dinv, b2, Wlin, ndot);

    graphred_kernel<<<NUM_GRAPHS, 256, 0, stream>>>(ndot, batch, blin, out);
}